// Round 4
// baseline (285.359 us; speedup 1.0000x reference)
//
#include <hip/hip_runtime.h>
#include <hip/hip_fp16.h>

// Problem constants (from reference)
#define N_SAMPLES 524288
#define N_FEATURES 64
#define N_GATES 64
#define N_OUTPUTS 8
#define BASE_COLS 66          // N_FEATURES + 2 (zero col, one col)
#define MAX_CONN 130          // BASE + N_GATES

// Tiling: 128 threads/block, each thread owns ONE packed fp16x2 LDS word = 2 samples.
#define TPB 256               // samples per block
#define NW 128                // words per row (= threads per block)
#define STR 129               // LDS row stride in words (NW+1: staging writes conflict-free)

// Liveness-compacted LDS: CAP_ROWS physical rows, last row = write-only scratch.
// 77*129*4 = 39,732 B <= 40 KB -> 4 blocks/CU = 8 waves/CU = 2 waves/SIMD (2x TLP vs r3).
#define CAP_ROWS 77
#define SCRATCH_ROW (CAP_ROWS - 1)
#define DYN_LDS (CAP_ROWS * STR * 4)

// d_ws layout (re-poisoned 0xAA each call -> every region rewritten every call)
#define WS_GIDX 0             // int2[64]
#define WS_NCHK 1024          // int
#define WS_CROW 1056          // int2 {zero_row_off, one_row_off or -1}
#define WS_XMAP 2048          // int[64]  (X col -> row offset in words, or -1 if dead)
#define WS_OWH2 4096          // uint[65*8] (half2-broadcast weights, row 64 = zeros)
#define WS_ENT  8192          // int4[520] (chunked plan, 8/chunk, +1 dummy chunk for prefetch)

// ---------------------------------------------------------------------------
// Kernel 1: top-2 connection indices per gate, one wave per gate.
// softmax monotone + TEMPERATURE=1 -> top2 of probs == top2 of masked weights.
// Tie-break: lower index wins (matches jax.lax.top_k stable order).
// ---------------------------------------------------------------------------
__device__ inline void top2_ins(float x, int j, float& v1, int& i1, float& v2, int& i2) {
    bool gt1 = (x > v1) || (x == v1 && j < i1);
    bool gt2 = (x > v2) || (x == v2 && j < i2);
    if (gt1) { v2 = v1; i2 = i1; v1 = x; i1 = j; }
    else if (gt2) { v2 = x; i2 = j; }
}

__global__ __launch_bounds__(64) void topk_prep_kernel(const float* __restrict__ gw,
                                                       int2* __restrict__ gidx) {
    const int i = blockIdx.x;
    const int l = threadIdx.x;
    const float* w = gw + i * MAX_CONN;
    const int avail = BASE_COLS + i;

    float v1 = -1e30f, v2 = -1e30f;
    int   i1 = 0x7fffffff, i2 = 0x7fffffff;
    for (int s = 0; s < 3; ++s) {
        int j = l + 64 * s;
        if (j < avail) top2_ins(w[j], j, v1, i1, v2, i2);
    }
    #pragma unroll
    for (int d = 1; d < 64; d <<= 1) {
        float ov1 = __shfl_xor(v1, d);
        int   oi1 = __shfl_xor(i1, d);
        float ov2 = __shfl_xor(v2, d);
        int   oi2 = __shfl_xor(i2, d);
        top2_ins(ov1, oi1, v1, i1, v2, i2);
        top2_ins(ov2, oi2, v1, i1, v2, i2);
    }
    if (l == 0) gidx[i] = make_int2(i1, i2);
}

// ---------------------------------------------------------------------------
// Kernel 2: build chunked plan with live-range ROW REUSE.
// - chunk = maximal run of gates whose operand COLUMNS precede the run start
//   (padded to 8 with dummies reading the zero row, weight row 64 = zeros)
// - rows allocated only for referenced columns; freed when last reader passes
//   (within-chunk reuse is safe: all reads precede all writes in program order)
// - unread gate outputs -> SCRATCH_ROW (write-only)
// ---------------------------------------------------------------------------
__global__ __launch_bounds__(64) void plan_kernel(const int2* __restrict__ gidx,
                                                  const float* __restrict__ ow,
                                                  char* __restrict__ ws) {
    __shared__ int ga[N_GATES], gb[N_GATES];
    __shared__ int refcnt[MAX_CONN], cmap[MAX_CONN];
    const int t = threadIdx.x;

    unsigned int* owh = (unsigned int*)(ws + WS_OWH2);
    int2 p = gidx[t];
    ga[t] = p.x; gb[t] = p.y;

    #pragma unroll
    for (int o = 0; o < N_OUTPUTS; ++o) {
        unsigned short u = __half_as_ushort(__float2half(ow[t * N_OUTPUTS + o]));
        owh[t * N_OUTPUTS + o] = (unsigned int)u * 0x10001u;
    }
    if (t < N_OUTPUTS) owh[N_GATES * N_OUTPUTS + t] = 0u;

    refcnt[t] = 0; refcnt[t + 64] = 0;
    cmap[t] = -1;  cmap[t + 64] = -1;
    if (t < 2) { refcnt[128 + t] = 0; cmap[128 + t] = -1; }
    __syncthreads();

    if (t == 0) {
        for (int i = 0; i < N_GATES; ++i) { refcnt[ga[i]]++; refcnt[gb[i]]++; }

        int frees[CAP_ROWS]; int nfree = 0;
        for (int r = SCRATCH_ROW - 1; r >= 0; --r) frees[nfree++] = r;

        refcnt[64] += 1000000;                 // zero row: never freed (dummies read it)
        cmap[64] = frees[--nfree];
        if (refcnt[65] > 0) cmap[65] = frees[--nfree];
        for (int c = 0; c < 64; ++c) if (refcnt[c] > 0) cmap[c] = frees[--nfree];

        int* xmap = (int*)(ws + WS_XMAP);
        for (int c = 0; c < 64; ++c) xmap[c] = (cmap[c] >= 0) ? cmap[c] * STR : -1;
        *(int2*)(ws + WS_CROW) =
            make_int2(cmap[64] * STR, (cmap[65] >= 0) ? cmap[65] * STR : -1);

        int4* ent = (int4*)(ws + WS_ENT);
        const int zoff = cmap[64] * STR;
        int e = 0, i = 0;
        while (i < N_GATES) {
            int cs = i, limit = BASE_COLS + cs;
            while (i < N_GATES && ga[i] < limit && gb[i] < limit) ++i;
            for (int j = cs; j < i; ++j) {
                int ca = ga[j], cb = gb[j];
                int ra = cmap[ca] * STR, rb = cmap[cb] * STR;
                if (--refcnt[ca] == 0 && nfree < SCRATCH_ROW) frees[nfree++] = cmap[ca];
                if (--refcnt[cb] == 0 && nfree < SCRATCH_ROW) frees[nfree++] = cmap[cb];
                int ro = SCRATCH_ROW;
                if (refcnt[BASE_COLS + j] > 0 && nfree > 0) ro = frees[--nfree];
                cmap[BASE_COLS + j] = ro;
                ent[e++] = make_int4(ra, rb, ro * STR, j);
            }
            while (e & 7) ent[e++] = make_int4(zoff, zoff, SCRATCH_ROW * STR, N_GATES);
        }
        *(int*)(ws + WS_NCHK) = e >> 3;
        for (int j = 0; j < 8; ++j)            // extra dummy chunk: unconditional prefetch
            ent[e++] = make_int4(zoff, zoff, SCRATCH_ROW * STR, N_GATES);
    }
}

// ---------------------------------------------------------------------------
// Kernel 3: evaluate circuit. Dynamic LDS, liveness-compacted rows.
// Each thread touches only word offset +t -> no cross-thread deps, no conflicts.
// ---------------------------------------------------------------------------
__global__ __launch_bounds__(NW) void circuit_kernel(
    const float* __restrict__ X,
    const char*  __restrict__ ws,
    const float* __restrict__ scale,
    float*       __restrict__ out)
{
    extern __shared__ __half2 buf[];           // CAP_ROWS * STR words

    const int t = threadIdx.x;
    const long long s0 = (long long)blockIdx.x * TPB;

    const int4* ent = (const int4*)(ws + WS_ENT);
    const unsigned int* owh = (const unsigned int*)(ws + WS_OWH2);
    const int nc = *(const int*)(ws + WS_NCHK);
    const int2 crow = *(const int2*)(ws + WS_CROW);

    // ---- Stage live X columns into LDS, transposed + fp16-packed.
    // c4 = t&15 is per-thread constant -> one xmap int4 lookup up front.
    const int c4 = t & 15;
    const int jb = t >> 4;
    const int4 xm = ((const int4*)(ws + WS_XMAP))[c4];

    const float4* Xv = (const float4*)(X + s0 * N_FEATURES);
    #pragma unroll
    for (int k = 0; k < 16; ++k) {
        int j = 8 * k + jb;                    // word index 0..127
        float4 va = Xv[(2 * j)     * 16 + c4];
        float4 vb = Xv[(2 * j + 1) * 16 + c4];
        if (xm.x >= 0) buf[xm.x + j] = __halves2half2(__float2half(va.x), __float2half(vb.x));
        if (xm.y >= 0) buf[xm.y + j] = __halves2half2(__float2half(va.y), __float2half(vb.y));
        if (xm.z >= 0) buf[xm.z + j] = __halves2half2(__float2half(va.z), __float2half(vb.z));
        if (xm.w >= 0) buf[xm.w + j] = __halves2half2(__float2half(va.w), __float2half(vb.w));
    }
    buf[crow.x + t] = __halves2half2(__float2half(0.0f), __float2half(0.0f));
    if (crow.y >= 0) buf[crow.y + t] = __halves2half2(__float2half(1.0f), __float2half(1.0f));
    __syncthreads();

    const __half2 one2 = __halves2half2(__float2half(1.0f), __float2half(1.0f));
    __half2 acc[N_OUTPUTS];
    #pragma unroll
    for (int o = 0; o < N_OUTPUTS; ++o) acc[o] = __halves2half2(__float2half(0.0f), __float2half(0.0f));

    // ---- Chunked gate execution with next-chunk entry prefetch.
    int4 E[8];
    #pragma unroll
    for (int j = 0; j < 8; ++j) E[j] = ent[j];

    for (int c = 0; c < nc; ++c) {
        int4 En[8];
        #pragma unroll
        for (int j = 0; j < 8; ++j) En[j] = ent[(c + 1) * 8 + j];   // dummy chunk exists

        __half2 av[8], bv[8];
        #pragma unroll
        for (int j = 0; j < 8; ++j) {
            av[j] = buf[E[j].x + t];
            bv[j] = buf[E[j].y + t];
        }
        __half2 gv[8];
        #pragma unroll
        for (int j = 0; j < 8; ++j) {
            gv[j] = __hfma2(__hneg2(av[j]), bv[j], one2);   // 1 - a*b, 2 samples
            buf[E[j].z + t] = gv[j];
        }
        #pragma unroll
        for (int j = 0; j < 8; ++j) {
            const __half2* wrow = (const __half2*)(owh + E[j].w * N_OUTPUTS);
            #pragma unroll
            for (int o = 0; o < N_OUTPUTS; ++o)
                acc[o] = __hfma2(gv[j], wrow[o], acc[o]);
        }
        #pragma unroll
        for (int j = 0; j < 8; ++j) E[j] = En[j];
    }

    // ---- Epilogue: scale + coalesced store.
    float sc[N_OUTPUTS];
    #pragma unroll
    for (int o = 0; o < N_OUTPUTS; ++o) sc[o] = scale[o];

    float a0[N_OUTPUTS], a1[N_OUTPUTS];
    #pragma unroll
    for (int o = 0; o < N_OUTPUTS; ++o) {
        a0[o] = __low2float(acc[o])  * sc[o];
        a1[o] = __high2float(acc[o]) * sc[o];
    }
    float4* outv = (float4*)(out + (s0 + 2 * t) * N_OUTPUTS);
    outv[0] = make_float4(a0[0], a0[1], a0[2], a0[3]);
    outv[1] = make_float4(a0[4], a0[5], a0[6], a0[7]);
    outv[2] = make_float4(a1[0], a1[1], a1[2], a1[3]);
    outv[3] = make_float4(a1[4], a1[5], a1[6], a1[7]);
}

extern "C" void kernel_launch(void* const* d_in, const int* in_sizes, int n_in,
                              void* d_out, int out_size, void* d_ws, size_t ws_size,
                              hipStream_t stream) {
    const float* X     = (const float*)d_in[0];
    const float* gw    = (const float*)d_in[1];
    const float* ow    = (const float*)d_in[2];
    const float* scale = (const float*)d_in[3];
    float* out = (float*)d_out;

    char* ws = (char*)d_ws;
    int2* gidx = (int2*)(ws + WS_GIDX);

    topk_prep_kernel<<<N_GATES, 64, 0, stream>>>(gw, gidx);
    plan_kernel<<<1, 64, 0, stream>>>(gidx, ow, ws);

    int blocks = N_SAMPLES / TPB;              // 2048
    circuit_kernel<<<blocks, NW, DYN_LDS, stream>>>(X, ws, scale, out);
}